// Round 9
// baseline (178.935 us; speedup 1.0000x reference)
//
#include <hip/hip_runtime.h>
#include <hip/hip_bf16.h>

typedef unsigned short ushort_t;
typedef unsigned int uint_t;
typedef __attribute__((ext_vector_type(8))) short short8;
typedef __attribute__((ext_vector_type(4))) float f32x4;

#define NEG_VAL -1e10f

__device__ __forceinline__ ushort_t f2bf(float x) {
    uint_t u = __float_as_uint(x);
    uint_t r = (u + 0x7fffu + ((u >> 16) & 1u)) >> 16;
    return (ushort_t)r;
}

__device__ __forceinline__ uint_t pkbf(float a, float b) {
    return (uint_t)f2bf(a) | ((uint_t)f2bf(b) << 16);
}

// single-instruction packed fp32x2 -> bf16x2 (RNE), dst.lo = a, dst.hi = b
__device__ __forceinline__ uint_t cvtpk(float a, float b) {
    uint_t r;
    asm("v_cvt_pk_bf16_f32 %0, %1, %2" : "=v"(r) : "v"(a), "v"(b));
    return r;
}

__device__ __forceinline__ float tanh_fast(float x) {
    float e = __expf(2.0f * x);
    return 1.0f - 2.0f / (e + 1.0f);
}

// attn_w[:, 512:1024] (f32 [512][1024]) -> w2 bf16 [512][512]
__global__ void w2conv_kernel(const float* __restrict__ attn_w, ushort_t* __restrict__ w2) {
    int gid = blockIdx.x * 256 + threadIdx.x;  // 65536 quads
    int h = gid >> 7, q = gid & 127;
    float4 v = *(const float4*)(attn_w + (size_t)h * 1024 + 512 + q * 4);
    uint2 p;
    p.x = pkbf(v.x, v.y);
    p.y = pkbf(v.z, v.w);
    *(uint2*)(w2 + h * 512 + q * 4) = p;
}

// hb[b][h] = attn_b[h] + sum_k hidden[b,k] * attn_w[h,k]   (fp32 exact)
__global__ void hproj_kernel(const float* __restrict__ hidden,
                             const float* __restrict__ attn_w,
                             const float* __restrict__ attn_b,
                             float* __restrict__ hb) {
    int gid = blockIdx.x * 256 + threadIdx.x;  // 32768
    int b = gid >> 9, h = gid & 511;
    const float4* hp = (const float4*)(hidden + (size_t)b * 512);
    const float4* wp = (const float4*)(attn_w + (size_t)h * 1024);
    float a0 = 0.f, a1 = 0.f, a2 = 0.f, a3 = 0.f;
    #pragma unroll 4
    for (int i = 0; i < 128; i += 4) {
        float4 x0 = hp[i + 0], w0 = wp[i + 0];
        a0 += x0.x * w0.x + x0.y * w0.y + x0.z * w0.z + x0.w * w0.w;
        float4 x1 = hp[i + 1], w1 = wp[i + 1];
        a1 += x1.x * w1.x + x1.y * w1.y + x1.z * w1.z + x1.w * w1.w;
        float4 x2 = hp[i + 2], w2v = wp[i + 2];
        a2 += x2.x * w2v.x + x2.y * w2v.y + x2.z * w2v.z + x2.w * w2v.w;
        float4 x3 = hp[i + 3], w3 = wp[i + 3];
        a3 += x3.x * w3.x + x3.y * w3.y + x3.z * w3.z + x3.w * w3.w;
    }
    hb[gid] = attn_b[h] + ((a0 + a1) + (a2 + a3));
}

// GEMM, register-direct: 128(M) x 512(full N) per block, 8 waves (2M x 4N),
// wave tile 64x128, acc[4][8]. NO LDS staging, NO main-loop barriers.
// A: global->reg (fp32, cvt_pk to bf16), prefetched 1 k-step ahead.
// B: global(L2-hot w2)->reg, same step, hidden by SMT + MFMA.
// Epilogue: tanh(pre + hb) * v, reduce over 512 h -> logits.
__global__ __launch_bounds__(512, 1) void gemm_kernel(
    const float* __restrict__ enc,      // [65536][512] f32 (row = s*64+b)
    const ushort_t* __restrict__ w2,    // [512][512] bf16
    const float* __restrict__ hb,       // [64][512] f32
    const float* __restrict__ vw,       // [512] f32
    float* __restrict__ logits)         // [65536] f32 (= [s][b])
{
    __shared__ float red[4][128];

    const int tid = threadIdx.x;
    const int wv = tid >> 6, l = tid & 63;
    const int wm = wv >> 2, wn = wv & 3;
    const int lr = l & 15, lq = l >> 4;
    const size_t m0 = (size_t)blockIdx.x * 128;

    // A fragment bases: lane (lr,lq) owns A[row][k = kt*32 + lq*8 .. +8]
    const float* aB[4];
    #pragma unroll
    for (int mf = 0; mf < 4; mf++)
        aB[mf] = enc + (m0 + wm * 64 + mf * 16 + lr) * 512 + lq * 8;
    // B fragment bases: lane (lr,lq) owns W2[row][k = kt*32 + lq*8 .. +8]
    const ushort_t* bB[8];
    #pragma unroll
    for (int nf = 0; nf < 8; nf++)
        bB[nf] = w2 + (size_t)(wn * 128 + nf * 16 + lr) * 512 + lq * 8;

    f32x4 acc[4][8] = {};

    // A prefetch registers (cur/next), fully unrolled loop -> SSA renames
    f32x4 a0[4], a1[4], n0[4], n1[4];
    #pragma unroll
    for (int mf = 0; mf < 4; mf++) {
        a0[mf] = *(const f32x4*)(aB[mf]);
        a1[mf] = *(const f32x4*)(aB[mf] + 4);
    }

    #pragma unroll
    for (int kt = 0; kt < 16; ++kt) {
        // B loads for current step (L2-hot; latency covered by other wave's MFMA)
        short8 bf[8];
        #pragma unroll
        for (int nf = 0; nf < 8; nf++)
            bf[nf] = *(const short8*)(bB[nf] + kt * 32);
        // A prefetch next step (HBM/L3 latency hidden across full step)
        if (kt < 15) {
            #pragma unroll
            for (int mf = 0; mf < 4; mf++) {
                n0[mf] = *(const f32x4*)(aB[mf] + (kt + 1) * 32);
                n1[mf] = *(const f32x4*)(aB[mf] + (kt + 1) * 32 + 4);
            }
        }
        short8 af[4];
        #pragma unroll
        for (int mf = 0; mf < 4; mf++) {
            union { short8 s; uint_t u[4]; } t;
            t.u[0] = cvtpk(a0[mf][0], a0[mf][1]);
            t.u[1] = cvtpk(a0[mf][2], a0[mf][3]);
            t.u[2] = cvtpk(a1[mf][0], a1[mf][1]);
            t.u[3] = cvtpk(a1[mf][2], a1[mf][3]);
            af[mf] = t.s;
        }
        #pragma unroll
        for (int mf = 0; mf < 4; mf++)
            #pragma unroll
            for (int nf = 0; nf < 8; nf++)
                acc[mf][nf] = __builtin_amdgcn_mfma_f32_16x16x32_bf16(af[mf], bf[nf], acc[mf][nf], 0, 0, 0);
        if (kt < 15) {
            #pragma unroll
            for (int mf = 0; mf < 4; mf++) { a0[mf] = n0[mf]; a1[mf] = n1[mf]; }
        }
    }

    // ---- epilogue: tanh(pre + hb) * v, reduce over all 512 h ----
    float vv[8];
    #pragma unroll
    for (int nf = 0; nf < 8; nf++) vv[nf] = vw[wn * 128 + nf * 16 + lr];

    #pragma unroll
    for (int mf = 0; mf < 4; mf++) {
        #pragma unroll
        for (int r = 0; r < 4; r++) {
            int row = wm * 64 + mf * 16 + lq * 4 + r;   // 0..127
            int b = row & 63;
            const float* hbp = hb + b * 512 + wn * 128 + lr;
            float p = 0.f;
            #pragma unroll
            for (int nf = 0; nf < 8; nf++) {
                float x = acc[mf][nf][r] + hbp[nf * 16];
                p += tanh_fast(x) * vv[nf];
            }
            p += __shfl_xor(p, 1);
            p += __shfl_xor(p, 2);
            p += __shfl_xor(p, 4);
            p += __shfl_xor(p, 8);
            if (lr == 0) red[wn][row] = p;
        }
    }
    __syncthreads();
    if (tid < 128) {
        logits[m0 + tid] = (red[0][tid] + red[1][tid]) + (red[2][tid] + red[3][tid]);
    }
}

// Masked softmax over s for each b. logits layout [s][b], out [b][s].
__global__ void softmax_kernel(const float* __restrict__ logits,
                               const int* __restrict__ mask,
                               float* __restrict__ out) {
    __shared__ float sred[8];
    int b = blockIdx.x;
    int t = threadIdx.x;  // 256
    float vals[4];
    float mx = -INFINITY;
    #pragma unroll
    for (int i = 0; i < 4; i++) {
        int s = t + i * 256;
        float x = logits[s * 64 + b];
        if (mask[b * 1024 + s] == 0) x = NEG_VAL;
        vals[i] = x;
        mx = fmaxf(mx, x);
    }
    #pragma unroll
    for (int o = 32; o; o >>= 1) mx = fmaxf(mx, __shfl_xor(mx, o));
    int w = t >> 6;
    if ((t & 63) == 0) sred[w] = mx;
    __syncthreads();
    mx = fmaxf(fmaxf(sred[0], sred[1]), fmaxf(sred[2], sred[3]));
    float sum = 0.f;
    #pragma unroll
    for (int i = 0; i < 4; i++) {
        vals[i] = __expf(vals[i] - mx);
        sum += vals[i];
    }
    #pragma unroll
    for (int o = 32; o; o >>= 1) sum += __shfl_xor(sum, o);
    if ((t & 63) == 0) sred[4 + w] = sum;
    __syncthreads();
    float tot = (sred[4] + sred[5]) + (sred[6] + sred[7]);
    float inv = 1.0f / tot;
    #pragma unroll
    for (int i = 0; i < 4; i++) out[b * 1024 + t + i * 256] = vals[i] * inv;
}

extern "C" void kernel_launch(void* const* d_in, const int* in_sizes, int n_in,
                              void* d_out, int out_size, void* d_ws, size_t ws_size,
                              hipStream_t stream) {
    const float* hidden = (const float*)d_in[1];
    const float* enc    = (const float*)d_in[2];
    const int*   mask   = (const int*)d_in[3];
    const float* attn_w = (const float*)d_in[9];
    const float* attn_b = (const float*)d_in[10];
    const float* vw     = (const float*)d_in[11];
    float* out = (float*)d_out;

    char* ws = (char*)d_ws;
    ushort_t* w2  = (ushort_t*)ws;                   // 512 KB
    float* hb     = (float*)(ws + 512 * 1024);       // 128 KB
    float* logits = (float*)(ws + 640 * 1024);       // 256 KB

    w2conv_kernel<<<256, 256, 0, stream>>>(attn_w, w2);
    hproj_kernel<<<128, 256, 0, stream>>>(hidden, attn_w, attn_b, hb);
    gemm_kernel<<<512, 512, 0, stream>>>(enc, w2, hb, vw, logits);
    softmax_kernel<<<64, 256, 0, stream>>>(logits, mask, out);
}

// Round 10
// 104.273 us; speedup vs baseline: 1.7160x; 1.7160x over previous
//
#include <hip/hip_runtime.h>
#include <hip/hip_bf16.h>

typedef unsigned short ushort_t;
typedef unsigned int uint_t;
typedef __attribute__((ext_vector_type(8))) short short8;
typedef __attribute__((ext_vector_type(4))) float f32x4;

#define NEG_VAL -1e10f

#define GL16(gp, lp) __builtin_amdgcn_global_load_lds( \
    (const __attribute__((address_space(1))) uint_t*)(gp), \
    (__attribute__((address_space(3))) uint_t*)(lp), 16, 0, 0)

__device__ __forceinline__ ushort_t f2bf(float x) {
    uint_t u = __float_as_uint(x);
    uint_t r = (u + 0x7fffu + ((u >> 16) & 1u)) >> 16;
    return (ushort_t)r;
}

__device__ __forceinline__ uint_t pkbf(float a, float b) {
    return (uint_t)f2bf(a) | ((uint_t)f2bf(b) << 16);
}

// single-instruction packed fp32x2 -> bf16x2 (RNE), dst.lo = a, dst.hi = b
__device__ __forceinline__ uint_t cvtpk(float a, float b) {
    uint_t r;
    asm("v_cvt_pk_bf16_f32 %0, %1, %2" : "=v"(r) : "v"(a), "v"(b));
    return r;
}

__device__ __forceinline__ float tanh_fast(float x) {
    float e = __expf(2.0f * x);
    return 1.0f - 2.0f / (e + 1.0f);
}

// attn_w[:, 512:1024] (f32 [512][1024]) -> w2 bf16 [512][512]
__global__ void w2conv_kernel(const float* __restrict__ attn_w, ushort_t* __restrict__ w2) {
    int gid = blockIdx.x * 256 + threadIdx.x;  // 65536 quads
    int h = gid >> 7, q = gid & 127;
    float4 v = *(const float4*)(attn_w + (size_t)h * 1024 + 512 + q * 4);
    uint2 p;
    p.x = pkbf(v.x, v.y);
    p.y = pkbf(v.z, v.w);
    *(uint2*)(w2 + h * 512 + q * 4) = p;
}

// hb[b][h] = attn_b[h] + sum_k hidden[b,k] * attn_w[h,k]   (fp32 exact)
__global__ void hproj_kernel(const float* __restrict__ hidden,
                             const float* __restrict__ attn_w,
                             const float* __restrict__ attn_b,
                             float* __restrict__ hb) {
    int gid = blockIdx.x * 256 + threadIdx.x;  // 32768
    int b = gid >> 9, h = gid & 511;
    const float4* hp = (const float4*)(hidden + (size_t)b * 512);
    const float4* wp = (const float4*)(attn_w + (size_t)h * 1024);
    float a0 = 0.f, a1 = 0.f, a2 = 0.f, a3 = 0.f;
    #pragma unroll 4
    for (int i = 0; i < 128; i += 4) {
        float4 x0 = hp[i + 0], w0 = wp[i + 0];
        a0 += x0.x * w0.x + x0.y * w0.y + x0.z * w0.z + x0.w * w0.w;
        float4 x1 = hp[i + 1], w1 = wp[i + 1];
        a1 += x1.x * w1.x + x1.y * w1.y + x1.z * w1.z + x1.w * w1.w;
        float4 x2 = hp[i + 2], w2v = wp[i + 2];
        a2 += x2.x * w2v.x + x2.y * w2v.y + x2.z * w2v.z + x2.w * w2v.w;
        float4 x3 = hp[i + 3], w3 = wp[i + 3];
        a3 += x3.x * w3.x + x3.y * w3.y + x3.z * w3.z + x3.w * w3.w;
    }
    hb[gid] = attn_b[h] + ((a0 + a1) + (a2 + a3));
}

// GEMM: 64(M) x 256(N=h) tile per block. 4 waves (2M x 2N), wave tile 32x128.
// BK=32, double-buffered LDS, global_load_lds staging, 3 blocks/CU (m97 regime).
// A fp32 in LDS (8KB/buf), cvt_pk to bf16 on read. B bf16 (16KB/buf).
__global__ __launch_bounds__(256, 3) void gemm_kernel(
    const float* __restrict__ enc,      // [65536][512] f32 (row = s*64+b)
    const ushort_t* __restrict__ w2,    // [512][512] bf16
    const float* __restrict__ hb,       // [64][512] f32
    const float* __restrict__ vw,       // [512] f32
    float* __restrict__ part)           // [2][65536] f32
{
    __shared__ __align__(16) float As[2][64 * 32];       // 8 KB x2 fp32
    __shared__ __align__(16) ushort_t Bs[2][256 * 32];   // 16 KB x2 bf16
    __shared__ float red[2][64];

    const int tid = threadIdx.x;
    const int bid = blockIdx.x;
    // bijective XCD swizzle (2048 = 8 x 256): both nt of one mt adjacent, same XCD
    const int xcd = bid & 7, j = bid >> 3;          // j: 0..255
    const int mt = xcd * 128 + (j >> 1), nt = j & 1; // mt: 0..1023
    const size_t m0 = (size_t)mt * 64;
    const int h0 = nt * 256;

    const int wv = tid >> 6, l = tid & 63;
    const int wm = wv >> 1, wn = wv & 1;
    const int lr = l & 15, lq = l >> 4;

    // ---- A staging: 2 gloads/wave. chunk c = wv*2+i covers rows 8c..8c+7
    // lane l -> row = c*8 + (l>>3), slot p = l&7, source unit j = p ^ (row&7)
    const float* aG[2];
    uint_t aL[2];
    #pragma unroll
    for (int i = 0; i < 2; i++) {
        int c = wv * 2 + i;                 // 0..7
        int row = c * 8 + (l >> 3);         // 0..63
        int jj = (l & 7) ^ (l >> 3);
        aG[i] = enc + (m0 + row) * 512 + jj * 4;
        aL[i] = (uint_t)c * 1024;           // wave-uniform byte base
    }
    // ---- B staging: 4 gloads/wave. chunk c = wv*4+i covers rows 16c..16c+15
    // lane l -> row = c*16 + (l>>2), slot p = l&3, source unit j = p ^ ((row>>1)&3)
    const ushort_t* bG[4];
    uint_t bL[4];
    #pragma unroll
    for (int i = 0; i < 4; i++) {
        int c = wv * 4 + i;                 // 0..15
        int row = c * 16 + (l >> 2);        // 0..255
        int jj = (l & 3) ^ ((l >> 3) & 3);
        bG[i] = w2 + (size_t)(h0 + row) * 512 + jj * 8;
        bL[i] = (uint_t)c * 1024;
    }

    // ---- fragment read byte-offsets (inverse of same involutions) ----
    uint_t aoff0[2], aoff1[2], boff[8];
    #pragma unroll
    for (int mf = 0; mf < 2; mf++) {
        int r = wm * 32 + mf * 16 + lr;     // 0..63
        aoff0[mf] = (uint_t)r * 128 + (uint_t)(((lq * 2 + 0) ^ (r & 7)) * 16);
        aoff1[mf] = (uint_t)r * 128 + (uint_t)(((lq * 2 + 1) ^ (r & 7)) * 16);
    }
    #pragma unroll
    for (int nf = 0; nf < 8; nf++) {
        int r = wn * 128 + nf * 16 + lr;    // 0..255
        boff[nf] = (uint_t)r * 64 + (uint_t)((lq ^ ((r >> 1) & 3)) * 16);
    }

    #define STAGE(kt, buf) do { \
        _Pragma("unroll") \
        for (int i = 0; i < 2; i++) GL16(aG[i] + (kt) * 32, (char*)(&As[(buf)][0]) + aL[i]); \
        _Pragma("unroll") \
        for (int i = 0; i < 4; i++) GL16(bG[i] + (kt) * 32, (char*)(&Bs[(buf)][0]) + bL[i]); \
    } while (0)

    // prologue: stage k-tile 0
    STAGE(0, 0);
    __syncthreads();

    f32x4 acc[2][8] = {};

    #pragma unroll 2
    for (int kt = 0; kt < 16; ++kt) {
        const int cur = kt & 1;
        if (kt < 15) STAGE(kt + 1, cur ^ 1);
        short8 af[2], bfr[8];
        #pragma unroll
        for (int nf = 0; nf < 8; nf++)
            bfr[nf] = *(const short8*)((const char*)(&Bs[cur][0]) + boff[nf]);
        #pragma unroll
        for (int mf = 0; mf < 2; mf++) {
            f32x4 lo = *(const f32x4*)((const char*)(&As[cur][0]) + aoff0[mf]);
            f32x4 hi = *(const f32x4*)((const char*)(&As[cur][0]) + aoff1[mf]);
            union { short8 s; uint_t u[4]; } t;
            t.u[0] = cvtpk(lo[0], lo[1]);
            t.u[1] = cvtpk(lo[2], lo[3]);
            t.u[2] = cvtpk(hi[0], hi[1]);
            t.u[3] = cvtpk(hi[2], hi[3]);
            af[mf] = t.s;
        }
        #pragma unroll
        for (int mf = 0; mf < 2; mf++)
            #pragma unroll
            for (int nf = 0; nf < 8; nf++)
                acc[mf][nf] = __builtin_amdgcn_mfma_f32_16x16x32_bf16(af[mf], bfr[nf], acc[mf][nf], 0, 0, 0);
        __syncthreads();
    }
    #undef STAGE

    // ---- epilogue: tanh(pre + hb) * v, reduce over this block's 256 h ----
    float vv[8];
    #pragma unroll
    for (int nf = 0; nf < 8; nf++) vv[nf] = vw[h0 + wn * 128 + nf * 16 + lr];

    #pragma unroll
    for (int mf = 0; mf < 2; mf++) {
        #pragma unroll
        for (int r = 0; r < 4; r++) {
            int row = wm * 32 + mf * 16 + lq * 4 + r;   // 0..63 (= b)
            const float* hbp = hb + row * 512 + h0 + wn * 128 + lr;
            float p = 0.f;
            #pragma unroll
            for (int nf = 0; nf < 8; nf++) {
                float x = acc[mf][nf][r] + hbp[nf * 16];
                p += tanh_fast(x) * vv[nf];
            }
            p += __shfl_xor(p, 1);
            p += __shfl_xor(p, 2);
            p += __shfl_xor(p, 4);
            p += __shfl_xor(p, 8);
            if (lr == 0) red[wn][row] = p;
        }
    }
    __syncthreads();
    if (tid < 64) {
        part[(size_t)nt * 65536 + m0 + tid] = red[0][tid] + red[1][tid];
    }
}

// Masked softmax over s for each b. part layout [2][s*64+b], out [b][s].
__global__ void softmax_kernel(const float* __restrict__ part,
                               const int* __restrict__ mask,
                               float* __restrict__ out) {
    __shared__ float sred[8];
    int b = blockIdx.x;
    int t = threadIdx.x;  // 256
    float vals[4];
    float mx = -INFINITY;
    #pragma unroll
    for (int i = 0; i < 4; i++) {
        int s = t + i * 256;
        int row = s * 64 + b;
        float x = part[row] + part[65536 + row];
        if (mask[b * 1024 + s] == 0) x = NEG_VAL;
        vals[i] = x;
        mx = fmaxf(mx, x);
    }
    #pragma unroll
    for (int o = 32; o; o >>= 1) mx = fmaxf(mx, __shfl_xor(mx, o));
    int w = t >> 6;
    if ((t & 63) == 0) sred[w] = mx;
    __syncthreads();
    mx = fmaxf(fmaxf(sred[0], sred[1]), fmaxf(sred[2], sred[3]));
    float sum = 0.f;
    #pragma unroll
    for (int i = 0; i < 4; i++) {
        vals[i] = __expf(vals[i] - mx);
        sum += vals[i];
    }
    #pragma unroll
    for (int o = 32; o; o >>= 1) sum += __shfl_xor(sum, o);
    if ((t & 63) == 0) sred[4 + w] = sum;
    __syncthreads();
    float tot = (sred[4] + sred[5]) + (sred[6] + sred[7]);
    float inv = 1.0f / tot;
    #pragma unroll
    for (int i = 0; i < 4; i++) out[b * 1024 + t + i * 256] = vals[i] * inv;
}

extern "C" void kernel_launch(void* const* d_in, const int* in_sizes, int n_in,
                              void* d_out, int out_size, void* d_ws, size_t ws_size,
                              hipStream_t stream) {
    const float* hidden = (const float*)d_in[1];
    const float* enc    = (const float*)d_in[2];
    const int*   mask   = (const int*)d_in[3];
    const float* attn_w = (const float*)d_in[9];
    const float* attn_b = (const float*)d_in[10];
    const float* vw     = (const float*)d_in[11];
    float* out = (float*)d_out;

    char* ws = (char*)d_ws;
    ushort_t* w2 = (ushort_t*)ws;                    // 512 KB
    float* hb   = (float*)(ws + 512 * 1024);         // 128 KB
    float* part = (float*)(ws + 640 * 1024);         // 512 KB (2 x 65536 f32)

    w2conv_kernel<<<256, 256, 0, stream>>>(attn_w, w2);
    hproj_kernel<<<128, 256, 0, stream>>>(hidden, attn_w, attn_b, hb);
    gemm_kernel<<<2048, 256, 0, stream>>>(enc, w2, hb, vw, part);
    softmax_kernel<<<64, 256, 0, stream>>>(part, mask, out);
}

// Round 12
// 93.446 us; speedup vs baseline: 1.9149x; 1.1159x over previous
//
#include <hip/hip_runtime.h>
#include <hip/hip_bf16.h>

typedef unsigned short ushort_t;
typedef unsigned int uint_t;
typedef __attribute__((ext_vector_type(8))) short short8;
typedef __attribute__((ext_vector_type(4))) float f32x4;

#define NEG_VAL -1e10f

#define GL16(gp, lp) __builtin_amdgcn_global_load_lds( \
    (const __attribute__((address_space(1))) uint_t*)(gp), \
    (__attribute__((address_space(3))) uint_t*)(lp), 16, 0, 0)

__device__ __forceinline__ ushort_t f2bf(float x) {
    uint_t u = __float_as_uint(x);
    uint_t r = (u + 0x7fffu + ((u >> 16) & 1u)) >> 16;
    return (ushort_t)r;
}

__device__ __forceinline__ uint_t pkbf(float a, float b) {
    return (uint_t)f2bf(a) | ((uint_t)f2bf(b) << 16);
}

// single-instruction packed fp32x2 -> bf16x2 (RNE), dst.lo = a, dst.hi = b
__device__ __forceinline__ uint_t cvtpk(float a, float b) {
    uint_t r;
    asm("v_cvt_pk_bf16_f32 %0, %1, %2" : "=v"(r) : "v"(a), "v"(b));
    return r;
}

__device__ __forceinline__ float tanh_fast(float x) {
    float e = __expf(2.0f * x);
    return 1.0f - 2.0f / (e + 1.0f);
}

// attn_w[:, 512:1024] (f32 [512][1024]) -> w2 bf16 [512][512]
__global__ void w2conv_kernel(const float* __restrict__ attn_w, ushort_t* __restrict__ w2) {
    int gid = blockIdx.x * 256 + threadIdx.x;  // 65536 quads
    int h = gid >> 7, q = gid & 127;
    float4 v = *(const float4*)(attn_w + (size_t)h * 1024 + 512 + q * 4);
    uint2 p;
    p.x = pkbf(v.x, v.y);
    p.y = pkbf(v.z, v.w);
    *(uint2*)(w2 + h * 512 + q * 4) = p;
}

// hb[b][h] = attn_b[h] + sum_k hidden[b,k] * attn_w[h,k]   (fp32 exact)
__global__ void hproj_kernel(const float* __restrict__ hidden,
                             const float* __restrict__ attn_w,
                             const float* __restrict__ attn_b,
                             float* __restrict__ hb) {
    int gid = blockIdx.x * 256 + threadIdx.x;  // 32768
    int b = gid >> 9, h = gid & 511;
    const float4* hp = (const float4*)(hidden + (size_t)b * 512);
    const float4* wp = (const float4*)(attn_w + (size_t)h * 1024);
    float a0 = 0.f, a1 = 0.f, a2 = 0.f, a3 = 0.f;
    #pragma unroll 4
    for (int i = 0; i < 128; i += 4) {
        float4 x0 = hp[i + 0], w0 = wp[i + 0];
        a0 += x0.x * w0.x + x0.y * w0.y + x0.z * w0.z + x0.w * w0.w;
        float4 x1 = hp[i + 1], w1 = wp[i + 1];
        a1 += x1.x * w1.x + x1.y * w1.y + x1.z * w1.z + x1.w * w1.w;
        float4 x2 = hp[i + 2], w2v = wp[i + 2];
        a2 += x2.x * w2v.x + x2.y * w2v.y + x2.z * w2v.z + x2.w * w2v.w;
        float4 x3 = hp[i + 3], w3 = wp[i + 3];
        a3 += x3.x * w3.x + x3.y * w3.y + x3.z * w3.z + x3.w * w3.w;
    }
    hb[gid] = attn_b[h] + ((a0 + a1) + (a2 + a3));
}

// GEMM: 128(M) x 256(N=h) per block, BK=32, double-buffered, gload_lds staging.
// 512 threads = 8 waves (2M x 4N), wave tile 64x64 -> acc[4][4] (64 AGPR).
// 2 blocks/CU x 8 waves = 4 waves/SIMD (concurrency = the rate lever).
__global__ __launch_bounds__(512, 4) void gemm_kernel(
    const float* __restrict__ enc,      // [65536][512] f32 (row = s*64+b)
    const ushort_t* __restrict__ w2,    // [512][512] bf16
    const float* __restrict__ hb,       // [64][512] f32
    const float* __restrict__ vw,       // [512] f32
    float* __restrict__ part)           // [2][65536] f32
{
    __shared__ __align__(16) float As[2][128 * 32];      // 16 KB x2 fp32
    __shared__ __align__(16) ushort_t Bs[2][256 * 32];   // 16 KB x2 bf16
    __shared__ float red[4][128];                        // 2 KB

    const int tid = threadIdx.x;
    const int bid = blockIdx.x;
    // bijective XCD swizzle (1024 = 8 x 128): both nt of one mt adjacent, same XCD
    const int xcd = bid & 7, j = bid >> 3;           // j: 0..127
    const int mt = xcd * 64 + (j >> 1), nt = j & 1;  // mt: 0..511
    const size_t m0 = (size_t)mt * 128;
    const int h0 = nt * 256;

    const int wv = tid >> 6, l = tid & 63;
    const int wm = wv >> 2, wn = wv & 3;             // 2M x 4N
    const int lr = l & 15, lq = l >> 4;

    // ---- A staging: 2 gloads/thread. 16B-unit u = 512*i + tid (1024 units)
    // row = u>>3 (8 units/row), slot p = tid&7, source unit j = p ^ (row&7)
    // i=0: row = tid>>3 (0..63); i=1: row = 64 + (tid>>3) -> same (row&7).
    // global offset for i=1: +64 rows = +64*512 floats = +32768
    const float* aG = enc + (m0 + (tid >> 3)) * 512 + (((tid & 7) ^ ((tid >> 3) & 7)) << 2);
    const uint_t aLb = (uint_t)__builtin_amdgcn_readfirstlane(wv * 64) * 16;
    // ---- B staging: 2 gloads/thread. unit u = 512*i + tid
    // row = u>>2 (4 units/row), slot p = tid&3, source unit j = p ^ ((row>>1)&3)
    // i=0: row = tid>>2 (0..127); i=1: row = 128 + (tid>>2) -> same ((row>>1)&3).
    // global offset for i=1: +128 rows = +128*512 ushorts = +65536
    const ushort_t* bG = w2 + (size_t)(h0 + (tid >> 2)) * 512 + (((tid & 3) ^ ((tid >> 3) & 3)) << 3);
    const uint_t bLb = aLb;

    // ---- fragment read byte-offsets (inverse involutions); mf/nf via imm strides
    const int ra = wm * 64 + lr;                     // base A row (mf stride 16 rows = 2048B)
    const uint_t aoff0 = (uint_t)ra * 128 + (uint_t)(((lq * 2 + 0) ^ (ra & 7)) * 16);
    const uint_t aoff1 = (uint_t)ra * 128 + (uint_t)(((lq * 2 + 1) ^ (ra & 7)) * 16);
    const int rb = wn * 64 + lr;                     // base B row (nf stride 16 rows = 1024B)
    const uint_t boff = (uint_t)rb * 64 + (uint_t)((lq ^ ((rb >> 1) & 3)) * 16);

    #define STAGE(kt, buf) do { \
        GL16(aG + (kt) * 32,         (char*)(&As[(buf)][0]) + aLb); \
        GL16(aG + (kt) * 32 + 32768, (char*)(&As[(buf)][0]) + aLb + 8192); \
        GL16(bG + (kt) * 32,         (char*)(&Bs[(buf)][0]) + bLb); \
        GL16(bG + (kt) * 32 + 65536, (char*)(&Bs[(buf)][0]) + bLb + 8192); \
    } while (0)

    // prologue: stage k-tile 0
    STAGE(0, 0);
    __syncthreads();

    f32x4 acc[4][4] = {};

    #pragma unroll 2
    for (int kt = 0; kt < 16; ++kt) {
        const int cur = kt & 1;
        if (kt < 15) STAGE(kt + 1, cur ^ 1);
        short8 af[4], bfr[4];
        #pragma unroll
        for (int nf = 0; nf < 4; nf++)
            bfr[nf] = *(const short8*)((const char*)(&Bs[cur][0]) + boff + nf * 1024);
        #pragma unroll
        for (int mf = 0; mf < 4; mf++) {
            f32x4 lo = *(const f32x4*)((const char*)(&As[cur][0]) + aoff0 + mf * 2048);
            f32x4 hi = *(const f32x4*)((const char*)(&As[cur][0]) + aoff1 + mf * 2048);
            union { short8 s; uint_t u[4]; } t;
            t.u[0] = cvtpk(lo[0], lo[1]);
            t.u[1] = cvtpk(lo[2], lo[3]);
            t.u[2] = cvtpk(hi[0], hi[1]);
            t.u[3] = cvtpk(hi[2], hi[3]);
            af[mf] = t.s;
        }
        #pragma unroll
        for (int mf = 0; mf < 4; mf++)
            #pragma unroll
            for (int nf = 0; nf < 4; nf++)
                acc[mf][nf] = __builtin_amdgcn_mfma_f32_16x16x32_bf16(af[mf], bfr[nf], acc[mf][nf], 0, 0, 0);
        __syncthreads();
    }
    #undef STAGE

    // ---- epilogue: tanh(pre + hb) * v, reduce over this block's 256 h ----
    float vv[4];
    #pragma unroll
    for (int nf = 0; nf < 4; nf++) vv[nf] = vw[h0 + wn * 64 + nf * 16 + lr];

    #pragma unroll
    for (int mf = 0; mf < 4; mf++) {
        #pragma unroll
        for (int r = 0; r < 4; r++) {
            int row = wm * 64 + mf * 16 + lq * 4 + r;   // 0..127
            int b = row & 63;
            const float* hbp = hb + b * 512 + h0 + wn * 64 + lr;
            float p = 0.f;
            #pragma unroll
            for (int nf = 0; nf < 4; nf++) {
                float x = acc[mf][nf][r] + hbp[nf * 16];
                p += tanh_fast(x) * vv[nf];
            }
            p += __shfl_xor(p, 1);
            p += __shfl_xor(p, 2);
            p += __shfl_xor(p, 4);
            p += __shfl_xor(p, 8);
            if (lr == 0) red[wn][row] = p;   // wm=0 -> rows 0..63, wm=1 -> 64..127
        }
    }
    __syncthreads();
    if (tid < 128) {
        part[(size_t)nt * 65536 + m0 + tid] =
            (red[0][tid] + red[1][tid]) + (red[2][tid] + red[3][tid]);
    }
}

// Masked softmax over s for each b. part layout [2][s*64+b], out [b][s].
__global__ void softmax_kernel(const float* __restrict__ part,
                               const int* __restrict__ mask,
                               float* __restrict__ out) {
    __shared__ float sred[8];
    int b = blockIdx.x;
    int t = threadIdx.x;  // 256
    float vals[4];
    float mx = -INFINITY;
    #pragma unroll
    for (int i = 0; i < 4; i++) {
        int s = t + i * 256;
        int row = s * 64 + b;
        float x = part[row] + part[65536 + row];
        if (mask[b * 1024 + s] == 0) x = NEG_VAL;
        vals[i] = x;
        mx = fmaxf(mx, x);
    }
    #pragma unroll
    for (int o = 32; o; o >>= 1) mx = fmaxf(mx, __shfl_xor(mx, o));
    int w = t >> 6;
    if ((t & 63) == 0) sred[w] = mx;
    __syncthreads();
    mx = fmaxf(fmaxf(sred[0], sred[1]), fmaxf(sred[2], sred[3]));
    float sum = 0.f;
    #pragma unroll
    for (int i = 0; i < 4; i++) {
        vals[i] = __expf(vals[i] - mx);
        sum += vals[i];
    }
    #pragma unroll
    for (int o = 32; o; o >>= 1) sum += __shfl_xor(sum, o);
    if ((t & 63) == 0) sred[4 + w] = sum;
    __syncthreads();
    float tot = (sred[4] + sred[5]) + (sred[6] + sred[7]);
    float inv = 1.0f / tot;
    #pragma unroll
    for (int i = 0; i < 4; i++) out[b * 1024 + t + i * 256] = vals[i] * inv;
}

extern "C" void kernel_launch(void* const* d_in, const int* in_sizes, int n_in,
                              void* d_out, int out_size, void* d_ws, size_t ws_size,
                              hipStream_t stream) {
    const float* hidden = (const float*)d_in[1];
    const float* enc    = (const float*)d_in[2];
    const int*   mask   = (const int*)d_in[3];
    const float* attn_w = (const float*)d_in[9];
    const float* attn_b = (const float*)d_in[10];
    const float* vw     = (const float*)d_in[11];
    float* out = (float*)d_out;

    char* ws = (char*)d_ws;
    ushort_t* w2 = (ushort_t*)ws;                    // 512 KB
    float* hb   = (float*)(ws + 512 * 1024);         // 128 KB
    float* part = (float*)(ws + 640 * 1024);         // 512 KB (2 x 65536 f32)

    w2conv_kernel<<<256, 256, 0, stream>>>(attn_w, w2);
    hproj_kernel<<<128, 256, 0, stream>>>(hidden, attn_w, attn_b, hb);
    gemm_kernel<<<1024, 512, 0, stream>>>(enc, w2, hb, vw, part);
    softmax_kernel<<<64, 256, 0, stream>>>(part, mask, out);
}